// Round 4
// baseline (588.008 us; speedup 1.0000x reference)
//
#include <hip/hip_runtime.h>
#include <math.h>

typedef unsigned short u16;
typedef unsigned int   u32;

// ======================================================================
// K1: encoder (z = x @ W_enc^T + b_enc) + decoder (x_hat = z @ W_dec^T + b_dec)
//     blocks >= 2048: W_sindy/W_dec passthrough + transposed W_sindy (wt)
//     All fp32 I/O.
// ======================================================================
__global__ __launch_bounds__(256) void k1_encdec(
    const float* __restrict__ x, const float* __restrict__ Wenc, const float* __restrict__ benc,
    const float* __restrict__ Wdec, const float* __restrict__ bdec,
    const float* __restrict__ Wsin,
    float* __restrict__ out_z, float* __restrict__ out_xhat,
    float* __restrict__ out_Ws, float* __restrict__ out_Wd,
    float* __restrict__ z_ws, float* __restrict__ wt)
{
    int tid = threadIdx.x;
    int blk = blockIdx.x;

    if (blk >= 2048) {
        int t0 = (blk - 2048) * 256 + tid;   // 64 blocks -> 16384 threads
        if (t0 < 16256) {
            float v = Wsin[t0];
            out_Ws[t0] = v;                   // pass-through output
            int l = t0 / 1016;
            int d = t0 - l * 1016;
            wt[d * 16 + l] = v;               // transposed for K3a
        }
        if (t0 < 2048) out_Wd[t0] = Wdec[t0];
        return;
    }

    __shared__ float xs[16][128];     // 16 rows of x
    __shared__ float we[16][132];     // W_enc, padded stride
    __shared__ float wd[128][17];     // W_dec, padded stride
    __shared__ float zs[16][16];

    // stage x tile: 2048 floats = 512 float4
    {
        const float4* xv = (const float4*)x + (size_t)blk * 512;
        float* dst = &xs[0][0];
        float4 a = xv[tid], b = xv[tid + 256];
        dst[tid*4+0]=a.x; dst[tid*4+1]=a.y; dst[tid*4+2]=a.z; dst[tid*4+3]=a.w;
        dst[(tid+256)*4+0]=b.x; dst[(tid+256)*4+1]=b.y; dst[(tid+256)*4+2]=b.z; dst[(tid+256)*4+3]=b.w;
    }
    // stage W_enc: (16,128) row-major, 512 float4
    {
        const float4* wev = (const float4*)Wenc;
        #pragma unroll
        for (int h = 0; h < 2; ++h) {
            int vi = tid + h * 256;
            float4 v = wev[vi];
            int base = vi * 4, row = base >> 7, col = base & 127;
            we[row][col+0]=v.x; we[row][col+1]=v.y; we[row][col+2]=v.z; we[row][col+3]=v.w;
        }
    }
    // stage W_dec: (128,16) row-major, 512 float4
    {
        const float4* wdv = (const float4*)Wdec;
        #pragma unroll
        for (int h = 0; h < 2; ++h) {
            int vi = tid + h * 256;
            float4 v = wdv[vi];
            int base = vi * 4, row = base >> 4, col = base & 15;
            wd[row][col+0]=v.x; wd[row][col+1]=v.y; wd[row][col+2]=v.z; wd[row][col+3]=v.w;
        }
    }
    __syncthreads();

    // encoder: one (row,l) per thread
    {
        int r = tid >> 4, l = tid & 15;
        float s = 0.f;
        #pragma unroll 8
        for (int f = 0; f < 128; ++f) s += xs[r][f] * we[l][f];
        float zv = s + benc[l];
        zs[r][l] = zv;
        int zo = blk * 256 + tid;             // == (blk*16+r)*16 + l
        z_ws[zo]  = zv;
        out_z[zo] = zv;
    }
    __syncthreads();

    // decoder: 8 (row,f) per thread
    #pragma unroll
    for (int u = 0; u < 8; ++u) {
        int idx = u * 256 + tid;
        int rr = idx >> 7, f = idx & 127;
        float acc = bdec[f];
        #pragma unroll
        for (int ll = 0; ll < 16; ++ll) acc += zs[rr][ll] * wd[f][ll];
        out_xhat[(size_t)blk * 2048 + idx] = acc;
    }
}

// ======================================================================
// K2: Hilbert transform per (b,l) series, fp64 radix-2 FFT in LDS.
//     analytic = ifft(H .* fft(z)),  H[0]=0, H[1..1023]=2, H[1024..]=0
// ======================================================================
#define TWPAD(k) ((k) + ((k) >> 5))

__global__ __launch_bounds__(256) void k2_hilbert(
    const float* __restrict__ z_ws, float* __restrict__ a_ws, float* __restrict__ p_ws)
{
    __shared__ double re[2048], im[2048];
    __shared__ double twc[1056], tws[1056];

    int tid = threadIdx.x;
    int b = blockIdx.x >> 4, l = blockIdx.x & 15;
    const float* zp = z_ws + ((size_t)b * 2048) * 16 + l;

    for (int k = tid; k < 1024; k += 256) {
        double ang = -6.283185307179586476925286766559 * (double)k / 2048.0;
        double s_, c_;
        sincos(ang, &s_, &c_);
        twc[TWPAD(k)] = c_;
        tws[TWPAD(k)] = s_;
    }
    for (int t = tid; t < 2048; t += 256) {
        int j = __brev((u32)t) >> 21;             // 11-bit reversal
        re[j] = (double)zp[(size_t)t * 16];
        im[j] = 0.0;
    }
    __syncthreads();

    for (int half = 1; half < 2048; half <<= 1) {   // forward FFT (DIT)
        int step = 1024 / half;
        for (int m = tid; m < 1024; m += 256) {
            int j = m & (half - 1);
            int pos = ((m - j) << 1) + j;
            int ti = TWPAD(j * step);
            double wc = twc[ti], wsn = tws[ti];
            double ur = re[pos], ui = im[pos];
            double vr = re[pos + half], vi = im[pos + half];
            double tr = vr * wc - vi * wsn;
            double t2 = vr * wsn + vi * wc;
            re[pos] = ur + tr;        im[pos] = ui + t2;
            re[pos + half] = ur - tr; im[pos + half] = ui - t2;
        }
        __syncthreads();
    }

    for (int k = tid; k < 2048; k += 256) {         // hilbert filter
        double sc = (k == 0 || k >= 1024) ? 0.0 : 2.0;
        re[k] *= sc; im[k] *= sc;
    }
    __syncthreads();

    for (int t = tid; t < 2048; t += 256) {         // bit-reverse permute
        int j = __brev((u32)t) >> 21;
        if (j > t) {
            double a0 = re[t], b0 = im[t];
            re[t] = re[j]; im[t] = im[j];
            re[j] = a0;    im[j] = b0;
        }
    }
    __syncthreads();

    for (int half = 1; half < 2048; half <<= 1) {   // inverse FFT (conj twiddles)
        int step = 1024 / half;
        for (int m = tid; m < 1024; m += 256) {
            int j = m & (half - 1);
            int pos = ((m - j) << 1) + j;
            int ti = TWPAD(j * step);
            double wc = twc[ti], wsn = -tws[ti];
            double ur = re[pos], ui = im[pos];
            double vr = re[pos + half], vi = im[pos + half];
            double tr = vr * wc - vi * wsn;
            double t2 = vr * wsn + vi * wc;
            re[pos] = ur + tr;        im[pos] = ui + t2;
            re[pos + half] = ur - tr; im[pos + half] = ui - t2;
        }
        __syncthreads();
    }

    for (int t = tid; t < 2048; t += 256) {
        double rr = re[t] * (1.0 / 2048.0);
        double ii = im[t] * (1.0 / 2048.0);
        size_t o = ((size_t)b * 2048 + t) * 16 + l;
        a_ws[o] = (float)sqrt(rr * rr + ii * ii);
        p_ws[o] = (float)atan2(ii, rr);
    }
}

// ======================================================================
// K3a: y_hat = theta @ W_sindy^T + b_sindy  (128 blocks, 1 point/thread)
// ======================================================================
__device__ __forceinline__ void emit(float v, int& d, const float* __restrict__ wt,
                                     float (&acc)[16])
{
    const float* w = wt + d * 16;      // d compile-time after unroll -> uniform loads
    #pragma unroll
    for (int l = 0; l < 16; ++l) acc[l] = fmaf(v, w[l], acc[l]);
    ++d;
}

__global__ __launch_bounds__(256) void k3_yhat(
    const float* __restrict__ z_ws, const float* __restrict__ a_ws,
    const float* __restrict__ p_ws, const float* __restrict__ wt,
    const float* __restrict__ bsin, float* __restrict__ out_y)
{
    int tid = threadIdx.x;
    int bt = blockIdx.x * 256 + tid;
    float z[16], av[16], pv[16], acc[16];
    {
        const float4* p = (const float4*)(z_ws + (size_t)bt * 16);
        #pragma unroll
        for (int q = 0; q < 4; ++q) {
            float4 v = p[q];
            z[q*4+0]=v.x; z[q*4+1]=v.y; z[q*4+2]=v.z; z[q*4+3]=v.w;
        }
    }
    {
        const float4* p = (const float4*)(a_ws + (size_t)bt * 16);
        #pragma unroll
        for (int q = 0; q < 4; ++q) {
            float4 v = p[q];
            av[q*4+0]=v.x; av[q*4+1]=v.y; av[q*4+2]=v.z; av[q*4+3]=v.w;
        }
    }
    {
        const float4* p = (const float4*)(p_ws + (size_t)bt * 16);
        #pragma unroll
        for (int q = 0; q < 4; ++q) {
            float4 v = p[q];
            pv[q*4+0]=v.x; pv[q*4+1]=v.y; pv[q*4+2]=v.z; pv[q*4+3]=v.w;
        }
    }
    #pragma unroll
    for (int l = 0; l < 16; ++l) acc[l] = bsin[l];

    int d = 0;
    #pragma unroll
    for (int i = 0; i < 16; ++i) emit(z[i], d, wt, acc);                 // deg 1
    #pragma unroll
    for (int i = 0; i < 16; ++i)
        #pragma unroll
        for (int j = i; j < 16; ++j) emit(z[i] * z[j], d, wt, acc);      // deg 2
    #pragma unroll
    for (int i = 0; i < 16; ++i)
        #pragma unroll
        for (int j = i; j < 16; ++j) {
            float pij = z[i] * z[j];
            #pragma unroll
            for (int k = j; k < 16; ++k) emit(pij * z[k], d, wt, acc);   // deg 3
        }
    #pragma unroll
    for (int i = 0; i < 16; ++i) emit(z[i], d, wt, acc);                 // z
    #pragma unroll
    for (int i = 0; i < 16; ++i) emit(av[i], d, wt, acc);                // |analytic|
    #pragma unroll
    for (int i = 0; i < 16; ++i) emit(pv[i], d, wt, acc);                // angle

    float4* yp = (float4*)(out_y + (size_t)bt * 16);
    #pragma unroll
    for (int q = 0; q < 4; ++q) {
        float4 v;
        v.x = acc[q*4+0]; v.y = acc[q*4+1]; v.z = acc[q*4+2]; v.w = acc[q*4+3];
        yp[q] = v;
    }
}

// ======================================================================
// K3b: jac = broadcast(W_enc fp32) over [B,T]. Overwrites the entire jac
//      region (incl. the scratch carved from its head). Runs LAST.
// ======================================================================
__global__ __launch_bounds__(256) void k3_jac(
    const float* __restrict__ Wenc, float* __restrict__ out_jac)
{
    const float4* w4 = (const float4*)Wenc;   // 512 float4 = 2048 fp32
    float4* j4 = (float4*)out_jac;            // 16777216 float4
    int nth = gridDim.x * 256;
    int i0 = blockIdx.x * 256 + threadIdx.x;
    for (int i = i0; i < 16777216; i += nth) {
        j4[i] = w4[i & 511];                  // period 2048 fp32 == one W_enc
    }
}

// ======================================================================
extern "C" void kernel_launch(void* const* d_in, const int* in_sizes, int n_in,
                              void* d_out, int out_size, void* d_ws, size_t ws_size,
                              hipStream_t stream)
{
    const float* x  = (const float*)d_in[0];
    const float* We = (const float*)d_in[1];
    const float* be = (const float*)d_in[2];
    const float* Wd = (const float*)d_in[3];
    const float* bd = (const float*)d_in[4];
    const float* Ws = (const float*)d_in[5];
    const float* bs = (const float*)d_in[6];

    float* out  = (float*)d_out;
    float* o_y  = out;                 // [16,2048,16]
    float* o_xh = out + 524288;        // [16,2048,128]
    float* o_z  = out + 4718592;       // [16,2048,16]
    float* o_j  = out + 5242880;       // [16,2048,16,128]  (268 MB)
    float* o_Ws = out + 72351744;      // [16,1016]
    float* o_Wd = out + 72368000;      // [128,16]

    // fp32 scratch carved from the HEAD of the jac output region
    // (k3_jac overwrites it last; 16B-aligned; no d_ws dependence at all).
    float* z_ws = o_j;                 // 524288 fp32
    float* a_ws = o_j + 524288;        // 524288 fp32
    float* p_ws = o_j + 1048576;       // 524288 fp32
    float* wt   = o_j + 1572864;       // 16256 fp32 (W_sindy transposed)
    // total 6.36 MB << 268 MB jac region

    hipLaunchKernelGGL(k1_encdec, dim3(2112), dim3(256), 0, stream,
                       x, We, be, Wd, bd, Ws, o_z, o_xh, o_Ws, o_Wd, z_ws, wt);
    hipLaunchKernelGGL(k2_hilbert, dim3(256), dim3(256), 0, stream,
                       z_ws, a_ws, p_ws);
    hipLaunchKernelGGL(k3_yhat, dim3(128), dim3(256), 0, stream,
                       z_ws, a_ws, p_ws, wt, bs, o_y);
    hipLaunchKernelGGL(k3_jac, dim3(4096), dim3(256), 0, stream,
                       We, o_j);
}

// Round 6
// 423.726 us; speedup vs baseline: 1.3877x; 1.3877x over previous
//
#include <hip/hip_runtime.h>
#include <math.h>

typedef unsigned short u16;
typedef unsigned int   u32;
typedef __attribute__((ext_vector_type(4))) float f32x4;   // native vec for nontemporal

// ---------------- scratch layout (fp32 offsets relative to o_j) ----------------
// All scratch lives at the HEAD of the jac output region (268 MB, we own it).
// k3_jac runs LAST and overwrites the whole region with the broadcast.
#define OFF_ZWS   0          // z, [bt][16]        524288 f
#define OFF_AT    524288     // |analytic|, [16][32768] (transposed)
#define OFF_PT    1048576    // angle,      [16][32768]
#define OFF_WT    1572864    // W_sindy^T,  [1016][16]  16256 f
#define OFF_ZT    1589120    // z transposed [16][32768]
#define OFF_TWC   2113408    // 1024 doubles (cos), 8B-aligned
#define OFF_TWS   2115456    // 1024 doubles (sin)
#define OFF_PART  2117504    // partial y: [8][32768][16] = 4194304 f

// ======================================================================
// K1: encoder + decoder; tail blocks: W passthroughs, W_sindy^T, twiddles
// ======================================================================
__global__ __launch_bounds__(256) void k1_encdec(
    const float* __restrict__ x, const float* __restrict__ Wenc, const float* __restrict__ benc,
    const float* __restrict__ Wdec, const float* __restrict__ bdec,
    const float* __restrict__ Wsin,
    float* __restrict__ out_z, float* __restrict__ out_xhat,
    float* __restrict__ out_Ws, float* __restrict__ out_Wd,
    float* __restrict__ z_ws, float* __restrict__ z_t, float* __restrict__ wt,
    double* __restrict__ twc_g, double* __restrict__ tws_g)
{
    int tid = threadIdx.x;
    int blk = blockIdx.x;

    if (blk >= 2048) {
        int t0 = (blk - 2048) * 256 + tid;   // 68 blocks -> 17408 threads
        if (t0 < 16256) {
            float v = Wsin[t0];
            out_Ws[t0] = v;
            int l = t0 / 1016;
            int d = t0 - l * 1016;
            wt[d * 16 + l] = v;
        } else if (t0 < 17280) {             // 1024 twiddles, fp64, once
            int k = t0 - 16256;
            double ang = -6.283185307179586476925286766559 * (double)k / 2048.0;
            double s_, c_;
            sincos(ang, &s_, &c_);
            twc_g[k] = c_;
            tws_g[k] = s_;
        }
        if (t0 < 2048) out_Wd[t0] = Wdec[t0];
        return;
    }

    __shared__ float xs[16][128];
    __shared__ float we[16][132];
    __shared__ float wd[128][17];
    __shared__ float zs[16][16];

    {
        const float4* xv = (const float4*)x + (size_t)blk * 512;
        float* dst = &xs[0][0];
        float4 a = xv[tid], b = xv[tid + 256];
        dst[tid*4+0]=a.x; dst[tid*4+1]=a.y; dst[tid*4+2]=a.z; dst[tid*4+3]=a.w;
        dst[(tid+256)*4+0]=b.x; dst[(tid+256)*4+1]=b.y; dst[(tid+256)*4+2]=b.z; dst[(tid+256)*4+3]=b.w;
    }
    {
        const float4* wev = (const float4*)Wenc;
        #pragma unroll
        for (int h = 0; h < 2; ++h) {
            int vi = tid + h * 256;
            float4 v = wev[vi];
            int base = vi * 4, row = base >> 7, col = base & 127;
            we[row][col+0]=v.x; we[row][col+1]=v.y; we[row][col+2]=v.z; we[row][col+3]=v.w;
        }
    }
    {
        const float4* wdv = (const float4*)Wdec;
        #pragma unroll
        for (int h = 0; h < 2; ++h) {
            int vi = tid + h * 256;
            float4 v = wdv[vi];
            int base = vi * 4, row = base >> 4, col = base & 15;
            wd[row][col+0]=v.x; wd[row][col+1]=v.y; wd[row][col+2]=v.z; wd[row][col+3]=v.w;
        }
    }
    __syncthreads();

    {
        int r = tid >> 4, l = tid & 15;
        float s = 0.f;
        #pragma unroll 8
        for (int f = 0; f < 128; ++f) s += xs[r][f] * we[l][f];
        float zv = s + benc[l];
        zs[r][l] = zv;
        int zo = blk * 256 + tid;             // == (blk*16+r)*16 + l
        z_ws[zo]  = zv;
        out_z[zo] = zv;
        z_t[l * 32768 + blk * 16 + r] = zv;   // transposed copy for K2
    }
    __syncthreads();

    #pragma unroll
    for (int u = 0; u < 8; ++u) {
        int idx = u * 256 + tid;
        int rr = idx >> 7, f = idx & 127;
        float acc = bdec[f];
        #pragma unroll
        for (int ll = 0; ll < 16; ++ll) acc += zs[rr][ll] * wd[f][ll];
        out_xhat[(size_t)blk * 2048 + idx] = acc;
    }
}

// ======================================================================
// K2: Hilbert per (b,l) series. fp64 radix-2 FFT in LDS, 1024 threads.
//     Twiddles precomputed (k1 tail). All global I/O coalesced (transposed).
// ======================================================================
#define P64(i) ((i) + ((i) >> 4))

__global__ __launch_bounds__(1024) void k2_hilbert(
    const float* __restrict__ z_t, const double* __restrict__ twc_g,
    const double* __restrict__ tws_g,
    float* __restrict__ a_t, float* __restrict__ p_t)
{
    __shared__ double re[2176], im[2176];
    __shared__ double twc[1088], tws[1088];

    int tid = threadIdx.x;
    int b = blockIdx.x >> 4, l = blockIdx.x & 15;
    const size_t base = (size_t)l * 32768 + (size_t)b * 2048;
    const float* zp = z_t + base;

    if (tid < 1024) {
        twc[P64(tid)] = twc_g[tid];
        tws[P64(tid)] = tws_g[tid];
    }
    #pragma unroll
    for (int h = 0; h < 2; ++h) {
        int t = tid + h * 1024;
        int j = __brev((u32)t) >> 21;             // 11-bit reversal
        re[P64(j)] = (double)zp[t];
        im[P64(j)] = 0.0;
    }
    __syncthreads();

    // forward FFT (DIT): 1 butterfly per thread per stage
    for (int half = 1; half < 2048; half <<= 1) {
        int step = 1024 / half;
        int j = tid & (half - 1);
        int pos = ((tid - j) << 1) + j;
        int ti = P64(j * step);
        double wc = twc[ti], wsn = tws[ti];
        int pa = P64(pos), pb = P64(pos + half);
        double ur = re[pa], ui = im[pa];
        double vr = re[pb], vi = im[pb];
        double tr = vr * wc - vi * wsn;
        double t2 = vr * wsn + vi * wc;
        re[pa] = ur + tr; im[pa] = ui + t2;
        re[pb] = ur - tr; im[pb] = ui - t2;
        __syncthreads();
    }

    // hilbert filter: H[0]=0, H[1..1023]=2, H[1024..]=0
    #pragma unroll
    for (int h = 0; h < 2; ++h) {
        int k = tid + h * 1024;
        double sc = (k == 0 || k >= 1024) ? 0.0 : 2.0;
        re[P64(k)] *= sc; im[P64(k)] *= sc;
    }
    __syncthreads();

    // bit-reverse permute for inverse DIT
    #pragma unroll
    for (int h = 0; h < 2; ++h) {
        int t = tid + h * 1024;
        int j = __brev((u32)t) >> 21;
        if (j > t) {
            int pt_ = P64(t), pj = P64(j);
            double a0 = re[pt_], b0 = im[pt_];
            re[pt_] = re[pj]; im[pt_] = im[pj];
            re[pj] = a0;      im[pj] = b0;
        }
    }
    __syncthreads();

    // inverse FFT (conjugate twiddles)
    for (int half = 1; half < 2048; half <<= 1) {
        int step = 1024 / half;
        int j = tid & (half - 1);
        int pos = ((tid - j) << 1) + j;
        int ti = P64(j * step);
        double wc = twc[ti], wsn = -tws[ti];
        int pa = P64(pos), pb = P64(pos + half);
        double ur = re[pa], ui = im[pa];
        double vr = re[pb], vi = im[pb];
        double tr = vr * wc - vi * wsn;
        double t2 = vr * wsn + vi * wc;
        re[pa] = ur + tr; im[pa] = ui + t2;
        re[pb] = ur - tr; im[pb] = ui - t2;
        __syncthreads();
    }

    #pragma unroll
    for (int h = 0; h < 2; ++h) {
        int t = tid + h * 1024;
        double rr = re[P64(t)] * (1.0 / 2048.0);
        double ii = im[P64(t)] * (1.0 / 2048.0);
        a_t[base + t] = (float)sqrt(rr * rr + ii * ii);
        p_t[base + t] = (float)atan2(ii, rr);
    }
}

// ======================================================================
// K3a: y partials. 1024 blocks = 128 point-blocks x 8 feature-slices of 127.
//      Slice weights staged in LDS (broadcast ds_read). Guard is scalar+uniform.
// ======================================================================
__device__ __forceinline__ void emit(float v, int& d, int LO, const float* lw,
                                     float (&acc)[16])
{
    if ((unsigned)(d - LO) < 127u) {
        int base = (d - LO) << 4;
        #pragma unroll
        for (int l = 0; l < 16; ++l) acc[l] = fmaf(v, lw[base + l], acc[l]);
    }
    ++d;
}

__global__ __launch_bounds__(256) void k3_yhat(
    const float* __restrict__ z_ws, const float* __restrict__ a_t,
    const float* __restrict__ p_t, const float* __restrict__ wt,
    float* __restrict__ part)
{
    __shared__ float lw[2032];                // 127 features x 16
    int tid = threadIdx.x;
    int slice = blockIdx.x >> 7;              // 0..7
    int ptblk = blockIdx.x & 127;
    int LO = slice * 127;

    {   // stage slice weights: 508 float4
        const float4* src = (const float4*)(wt + LO * 16);
        float4* dst = (float4*)lw;
        for (int i = tid; i < 508; i += 256) dst[i] = src[i];
    }
    __syncthreads();

    int bt = ptblk * 256 + tid;
    float z[16], av[16], pv[16], acc[16];
    {
        const float4* p = (const float4*)(z_ws + (size_t)bt * 16);
        #pragma unroll
        for (int q = 0; q < 4; ++q) {
            float4 v = p[q];
            z[q*4+0]=v.x; z[q*4+1]=v.y; z[q*4+2]=v.z; z[q*4+3]=v.w;
        }
    }
    if (LO >= 880) {                          // only slice 7 touches av/pv
        #pragma unroll
        for (int l = 0; l < 16; ++l) {
            av[l] = a_t[(size_t)l * 32768 + bt];
            pv[l] = p_t[(size_t)l * 32768 + bt];
        }
    } else {
        #pragma unroll
        for (int l = 0; l < 16; ++l) { av[l] = 0.f; pv[l] = 0.f; }
    }
    #pragma unroll
    for (int l = 0; l < 16; ++l) acc[l] = 0.f;   // bias added in reduce

    int d = 0;
    #pragma unroll
    for (int i = 0; i < 16; ++i) emit(z[i], d, LO, lw, acc);              // deg 1
    #pragma unroll
    for (int i = 0; i < 16; ++i)
        #pragma unroll
        for (int j = i; j < 16; ++j) emit(z[i] * z[j], d, LO, lw, acc);   // deg 2
    #pragma unroll
    for (int i = 0; i < 16; ++i)
        #pragma unroll
        for (int j = i; j < 16; ++j) {
            float pij = z[i] * z[j];
            #pragma unroll
            for (int k = j; k < 16; ++k) emit(pij * z[k], d, LO, lw, acc); // deg 3
        }
    #pragma unroll
    for (int i = 0; i < 16; ++i) emit(z[i], d, LO, lw, acc);              // z
    #pragma unroll
    for (int i = 0; i < 16; ++i) emit(av[i], d, LO, lw, acc);             // |analytic|
    #pragma unroll
    for (int i = 0; i < 16; ++i) emit(pv[i], d, LO, lw, acc);             // angle

    float4* pp = (float4*)(part + (size_t)slice * 524288 + (size_t)bt * 16);
    #pragma unroll
    for (int q = 0; q < 4; ++q) {
        float4 v;
        v.x = acc[q*4+0]; v.y = acc[q*4+1]; v.z = acc[q*4+2]; v.w = acc[q*4+3];
        pp[q] = v;
    }
}

// ======================================================================
// K3b: reduce 8 partials + bias -> y_hat. 131072 float4 outputs.
// ======================================================================
__global__ __launch_bounds__(256) void k3_reduce(
    const float* __restrict__ part, const float* __restrict__ bsin,
    float* __restrict__ out_y)
{
    int i0 = blockIdx.x * 256 + threadIdx.x;      // float4 index
    float4 s = ((const float4*)bsin)[i0 & 3];
    const float4* p4 = (const float4*)part;
    #pragma unroll
    for (int sl = 0; sl < 8; ++sl) {
        float4 v = p4[(size_t)sl * 131072 + i0];
        s.x += v.x; s.y += v.y; s.z += v.z; s.w += v.w;
    }
    ((float4*)out_y)[i0] = s;
}

// ======================================================================
// K3c: jac broadcast. Grid-stride multiple of 512 float4 -> source index
//      is loop-invariant (one load, then pure nontemporal stores). LAST.
// ======================================================================
__global__ __launch_bounds__(256) void k3_jac(
    const float* __restrict__ Wenc, float* __restrict__ out_jac)
{
    int nth = gridDim.x * 256;                // 2097152 = 512*4096
    int i0 = blockIdx.x * 256 + threadIdx.x;
    const float* wsrc = Wenc + (size_t)(i0 & 511) * 4;   // invariant: nth % 512 == 0
    f32x4 w;
    w.x = wsrc[0]; w.y = wsrc[1]; w.z = wsrc[2]; w.w = wsrc[3];
    f32x4* j4 = (f32x4*)out_jac;              // 16777216 vec4 slots
    for (int i = i0; i < 16777216; i += nth) {
        __builtin_nontemporal_store(w, j4 + i);
    }
}

// ======================================================================
extern "C" void kernel_launch(void* const* d_in, const int* in_sizes, int n_in,
                              void* d_out, int out_size, void* d_ws, size_t ws_size,
                              hipStream_t stream)
{
    const float* x  = (const float*)d_in[0];
    const float* We = (const float*)d_in[1];
    const float* be = (const float*)d_in[2];
    const float* Wd = (const float*)d_in[3];
    const float* bd = (const float*)d_in[4];
    const float* Ws = (const float*)d_in[5];
    const float* bs = (const float*)d_in[6];

    float* out  = (float*)d_out;
    float* o_y  = out;                 // [16,2048,16]
    float* o_xh = out + 524288;        // [16,2048,128]
    float* o_z  = out + 4718592;       // [16,2048,16]
    float* o_j  = out + 5242880;       // [16,2048,16,128]  (268 MB)
    float* o_Ws = out + 72351744;      // [16,1016]
    float* o_Wd = out + 72368000;      // [128,16]

    float*  z_ws  = o_j + OFF_ZWS;
    float*  a_t   = o_j + OFF_AT;
    float*  p_t   = o_j + OFF_PT;
    float*  wt    = o_j + OFF_WT;
    float*  z_t   = o_j + OFF_ZT;
    double* twc_g = (double*)(o_j + OFF_TWC);
    double* tws_g = (double*)(o_j + OFF_TWS);
    float*  part  = o_j + OFF_PART;    // ends at 6.3M floats << 67.1M region

    hipLaunchKernelGGL(k1_encdec, dim3(2116), dim3(256), 0, stream,
                       x, We, be, Wd, bd, Ws, o_z, o_xh, o_Ws, o_Wd,
                       z_ws, z_t, wt, twc_g, tws_g);
    hipLaunchKernelGGL(k2_hilbert, dim3(256), dim3(1024), 0, stream,
                       z_t, twc_g, tws_g, a_t, p_t);
    hipLaunchKernelGGL(k3_yhat, dim3(1024), dim3(256), 0, stream,
                       z_ws, a_t, p_t, wt, part);
    hipLaunchKernelGGL(k3_reduce, dim3(512), dim3(256), 0, stream,
                       part, bs, o_y);
    hipLaunchKernelGGL(k3_jac, dim3(8192), dim3(256), 0, stream,
                       We, o_j);
}

// Round 7
// 414.027 us; speedup vs baseline: 1.4202x; 1.0234x over previous
//
#include <hip/hip_runtime.h>
#include <math.h>

typedef unsigned short u16;
typedef unsigned int   u32;
typedef __attribute__((ext_vector_type(4))) float f32x4;   // native vec for nontemporal

// ---------------- scratch layout (fp32 offsets relative to o_j) ----------------
// All scratch lives at the HEAD of the jac output region (268 MB, we own it).
// k3_jac runs LAST and overwrites the whole region with the broadcast.
#define OFF_ZWS   0          // z, [bt][16]        524288 f
#define OFF_AT    524288     // |analytic|, [16][32768] (transposed)
#define OFF_PT    1048576    // angle,      [16][32768]
#define OFF_WT    1572864    // W_sindy^T,  [1016][16]  16256 f
#define OFF_ZT    1589120    // z transposed [16][32768]
#define OFF_TWC   2113408    // 1024 doubles (cos), 8B-aligned
#define OFF_TWS   2115456    // 1024 doubles (sin)
#define OFF_PART  2117504    // partial y: [8][32768][16] = 4194304 f

// ======================================================================
// K1: encoder + decoder; tail blocks: W passthroughs, W_sindy^T, twiddles
// ======================================================================
__global__ __launch_bounds__(256) void k1_encdec(
    const float* __restrict__ x, const float* __restrict__ Wenc, const float* __restrict__ benc,
    const float* __restrict__ Wdec, const float* __restrict__ bdec,
    const float* __restrict__ Wsin,
    float* __restrict__ out_z, float* __restrict__ out_xhat,
    float* __restrict__ out_Ws, float* __restrict__ out_Wd,
    float* __restrict__ z_ws, float* __restrict__ z_t, float* __restrict__ wt,
    double* __restrict__ twc_g, double* __restrict__ tws_g)
{
    int tid = threadIdx.x;
    int blk = blockIdx.x;

    if (blk >= 2048) {
        int t0 = (blk - 2048) * 256 + tid;   // 68 blocks -> 17408 threads
        if (t0 < 16256) {
            float v = Wsin[t0];
            out_Ws[t0] = v;
            int l = t0 / 1016;
            int d = t0 - l * 1016;
            wt[d * 16 + l] = v;
        } else if (t0 < 17280) {             // 1024 twiddles, fp64, once
            int k = t0 - 16256;
            double ang = -6.283185307179586476925286766559 * (double)k / 2048.0;
            double s_, c_;
            sincos(ang, &s_, &c_);
            twc_g[k] = c_;
            tws_g[k] = s_;
        }
        if (t0 < 2048) out_Wd[t0] = Wdec[t0];
        return;
    }

    __shared__ float xs[16][128];
    __shared__ float we[16][132];
    __shared__ float wd[128][17];
    __shared__ float zs[16][16];

    {
        const float4* xv = (const float4*)x + (size_t)blk * 512;
        float* dst = &xs[0][0];
        float4 a = xv[tid], b = xv[tid + 256];
        dst[tid*4+0]=a.x; dst[tid*4+1]=a.y; dst[tid*4+2]=a.z; dst[tid*4+3]=a.w;
        dst[(tid+256)*4+0]=b.x; dst[(tid+256)*4+1]=b.y; dst[(tid+256)*4+2]=b.z; dst[(tid+256)*4+3]=b.w;
    }
    {
        const float4* wev = (const float4*)Wenc;
        #pragma unroll
        for (int h = 0; h < 2; ++h) {
            int vi = tid + h * 256;
            float4 v = wev[vi];
            int base = vi * 4, row = base >> 7, col = base & 127;
            we[row][col+0]=v.x; we[row][col+1]=v.y; we[row][col+2]=v.z; we[row][col+3]=v.w;
        }
    }
    {
        const float4* wdv = (const float4*)Wdec;
        #pragma unroll
        for (int h = 0; h < 2; ++h) {
            int vi = tid + h * 256;
            float4 v = wdv[vi];
            int base = vi * 4, row = base >> 4, col = base & 15;
            wd[row][col+0]=v.x; wd[row][col+1]=v.y; wd[row][col+2]=v.z; wd[row][col+3]=v.w;
        }
    }
    __syncthreads();

    {
        int r = tid >> 4, l = tid & 15;
        float s = 0.f;
        #pragma unroll 8
        for (int f = 0; f < 128; ++f) s += xs[r][f] * we[l][f];
        float zv = s + benc[l];
        zs[r][l] = zv;
        int zo = blk * 256 + tid;             // == (blk*16+r)*16 + l
        z_ws[zo]  = zv;
        out_z[zo] = zv;
    }
    __syncthreads();

    // transposed z copy for K2 (coalesced 64B runs: r2 fastest)
    {
        int l2 = tid >> 4, r2 = tid & 15;
        z_t[l2 * 32768 + blk * 16 + r2] = zs[r2][l2];
    }

    #pragma unroll
    for (int u = 0; u < 8; ++u) {
        int idx = u * 256 + tid;
        int rr = idx >> 7, f = idx & 127;
        float acc = bdec[f];
        #pragma unroll
        for (int ll = 0; ll < 16; ++ll) acc += zs[rr][ll] * wd[f][ll];
        out_xhat[(size_t)blk * 2048 + idx] = acc;
    }
}

// ======================================================================
// K2: Hilbert per (b,l) series, fp64, interleaved-complex LDS.
//     DIF forward (natural in -> bitrev out), Hilbert filter applied in
//     bit-reversed domain (k==0 -> pos 0; k>=1024 <-> odd pos), then
//     DIT inverse (bitrev in -> natural out). No permute passes.
//     1/2048 folded into the filter scale.
// ======================================================================
__global__ __launch_bounds__(1024) void k2_hilbert(
    const float* __restrict__ z_t, const double* __restrict__ twc_g,
    const double* __restrict__ tws_g,
    float* __restrict__ a_t, float* __restrict__ p_t)
{
    __shared__ double2 c[2048];    // interleaved complex, ds_*_b128
    __shared__ double2 tw[1024];   // (cos,sin) of -2*pi*k/2048

    int tid = threadIdx.x;
    int b = blockIdx.x >> 4, l = blockIdx.x & 15;
    const size_t base = (size_t)l * 32768 + (size_t)b * 2048;
    const float* zp = z_t + base;

    {
        double2 t; t.x = twc_g[tid]; t.y = tws_g[tid];
        tw[tid] = t;
    }
    {
        double2 v0; v0.x = (double)zp[tid];        v0.y = 0.0;
        double2 v1; v1.x = (double)zp[tid + 1024]; v1.y = 0.0;
        c[tid] = v0;
        c[tid + 1024] = v1;
    }
    __syncthreads();

    // forward DIF: half = 1024 .. 1; butterfly u'=u+v, v'=(u-v)*W^(j*step)
    for (int half = 1024; half >= 1; half >>= 1) {
        int step = 1024 / half;
        int j = tid & (half - 1);
        int pos = ((tid - j) << 1) + j;
        double2 u = c[pos], v = c[pos + half];
        double2 w = tw[j * step];
        double2 s, dsc;
        s.x = u.x + v.x;  s.y = u.y + v.y;
        double br = u.x - v.x, bi = u.y - v.y;
        dsc.x = br * w.x - bi * w.y;
        dsc.y = br * w.y + bi * w.x;
        c[pos] = s;
        c[pos + half] = dsc;
        __syncthreads();
    }

    // Hilbert filter in bitrev domain, 1/N folded in:
    // array pos p holds X[bitrev(p)]; k==0 <-> p==0, k>=1024 <-> p odd.
    #pragma unroll
    for (int h = 0; h < 2; ++h) {
        int t = tid + h * 1024;
        double sc = (t == 0 || (t & 1)) ? 0.0 : (2.0 / 2048.0);
        double2 v = c[t];
        v.x *= sc; v.y *= sc;
        c[t] = v;
    }
    __syncthreads();

    // inverse DIT: half = 1 .. 1024; t = v*conj(W); u'=u+t, v'=u-t
    for (int half = 1; half <= 1024; half <<= 1) {
        int step = 1024 / half;
        int j = tid & (half - 1);
        int pos = ((tid - j) << 1) + j;
        double2 u = c[pos], v = c[pos + half];
        double2 w = tw[j * step];
        double tr = v.x * w.x + v.y * w.y;    // v * conj(w)
        double ti = v.y * w.x - v.x * w.y;
        double2 p0, p1;
        p0.x = u.x + tr; p0.y = u.y + ti;
        p1.x = u.x - tr; p1.y = u.y - ti;
        c[pos] = p0;
        c[pos + half] = p1;
        __syncthreads();
    }

    #pragma unroll
    for (int h = 0; h < 2; ++h) {
        int t = tid + h * 1024;
        double2 v = c[t];
        a_t[base + t] = (float)sqrt(v.x * v.x + v.y * v.y);
        p_t[base + t] = (float)atan2(v.y, v.x);
    }
}

// ======================================================================
// K3a: y partials. 256 blocks = 32 pt-groups x 8 slices of 127 features.
//      4 points/thread: weight row read once per feature, applied to 4 accs.
//      Feature products computed INSIDE the uniform slice guard.
// ======================================================================
#define EMIT4(EXPR) do {                                                    \
    if ((unsigned)(d - LO) < 127u) {                                        \
        float vv[4];                                                        \
        _Pragma("unroll") for (int p = 0; p < 4; ++p) vv[p] = (EXPR);       \
        int bb = (d - LO) << 4;                                             \
        _Pragma("unroll") for (int l = 0; l < 16; ++l) {                    \
            float w = lw[bb + l];                                           \
            _Pragma("unroll") for (int p = 0; p < 4; ++p)                   \
                acc[p][l] = fmaf(vv[p], w, acc[p][l]);                      \
        }                                                                   \
    }                                                                       \
    ++d;                                                                    \
} while (0)

__global__ __launch_bounds__(256) void k3_yhat(
    const float* __restrict__ z_ws, const float* __restrict__ a_t,
    const float* __restrict__ p_t, const float* __restrict__ wt,
    float* __restrict__ part)
{
    __shared__ float lw[2032];                // 127 features x 16
    int tid = threadIdx.x;
    int slice = blockIdx.x >> 5;              // 0..7
    int ptgrp = blockIdx.x & 31;              // 0..31
    int LO = slice * 127;
    int base = ptgrp * 1024;                  // 1024 points per block

    {   // stage slice weights: 508 float4
        const float4* src = (const float4*)(wt + LO * 16);
        float4* dst = (float4*)lw;
        for (int i = tid; i < 508; i += 256) dst[i] = src[i];
    }
    __syncthreads();

    float z[4][16], av[4][16], pv[4][16], acc[4][16];
    #pragma unroll
    for (int p = 0; p < 4; ++p) {
        int bt = base + p * 256 + tid;
        const float4* zp = (const float4*)(z_ws + (size_t)bt * 16);
        #pragma unroll
        for (int q = 0; q < 4; ++q) {
            float4 v = zp[q];
            z[p][q*4+0]=v.x; z[p][q*4+1]=v.y; z[p][q*4+2]=v.z; z[p][q*4+3]=v.w;
        }
    }
    if (LO >= 880) {                          // only slice 7 touches av/pv
        #pragma unroll
        for (int p = 0; p < 4; ++p) {
            int bt = base + p * 256 + tid;
            #pragma unroll
            for (int l = 0; l < 16; ++l) {
                av[p][l] = a_t[(size_t)l * 32768 + bt];
                pv[p][l] = p_t[(size_t)l * 32768 + bt];
            }
        }
    } else {
        #pragma unroll
        for (int p = 0; p < 4; ++p)
            #pragma unroll
            for (int l = 0; l < 16; ++l) { av[p][l] = 0.f; pv[p][l] = 0.f; }
    }
    #pragma unroll
    for (int p = 0; p < 4; ++p)
        #pragma unroll
        for (int l = 0; l < 16; ++l) acc[p][l] = 0.f;   // bias added in reduce

    int d = 0;
    #pragma unroll
    for (int i = 0; i < 16; ++i) EMIT4(z[p][i]);                          // deg 1
    #pragma unroll
    for (int i = 0; i < 16; ++i)
        #pragma unroll
        for (int j = i; j < 16; ++j) EMIT4(z[p][i] * z[p][j]);            // deg 2
    #pragma unroll
    for (int i = 0; i < 16; ++i)
        #pragma unroll
        for (int j = i; j < 16; ++j)
            #pragma unroll
            for (int k = j; k < 16; ++k) EMIT4(z[p][i] * z[p][j] * z[p][k]); // deg 3
    #pragma unroll
    for (int i = 0; i < 16; ++i) EMIT4(z[p][i]);                          // z
    #pragma unroll
    for (int i = 0; i < 16; ++i) EMIT4(av[p][i]);                         // |analytic|
    #pragma unroll
    for (int i = 0; i < 16; ++i) EMIT4(pv[p][i]);                         // angle

    #pragma unroll
    for (int p = 0; p < 4; ++p) {
        int bt = base + p * 256 + tid;
        float4* pp = (float4*)(part + (size_t)slice * 524288 + (size_t)bt * 16);
        #pragma unroll
        for (int q = 0; q < 4; ++q) {
            float4 v;
            v.x = acc[p][q*4+0]; v.y = acc[p][q*4+1];
            v.z = acc[p][q*4+2]; v.w = acc[p][q*4+3];
            pp[q] = v;
        }
    }
}

// ======================================================================
// K3b: reduce 8 partials + bias -> y_hat. 131072 float4 outputs.
// ======================================================================
__global__ __launch_bounds__(256) void k3_reduce(
    const float* __restrict__ part, const float* __restrict__ bsin,
    float* __restrict__ out_y)
{
    int i0 = blockIdx.x * 256 + threadIdx.x;      // float4 index
    float4 s = ((const float4*)bsin)[i0 & 3];
    const float4* p4 = (const float4*)part;
    #pragma unroll
    for (int sl = 0; sl < 8; ++sl) {
        float4 v = p4[(size_t)sl * 131072 + i0];
        s.x += v.x; s.y += v.y; s.z += v.z; s.w += v.w;
    }
    ((float4*)out_y)[i0] = s;
}

// ======================================================================
// K3c: jac broadcast. Grid-stride multiple of 512 float4 -> source index
//      is loop-invariant (one load, then pure nontemporal stores). LAST.
// ======================================================================
__global__ __launch_bounds__(256) void k3_jac(
    const float* __restrict__ Wenc, float* __restrict__ out_jac)
{
    int nth = gridDim.x * 256;                // 2097152 = 512*4096
    int i0 = blockIdx.x * 256 + threadIdx.x;
    const float* wsrc = Wenc + (size_t)(i0 & 511) * 4;   // invariant: nth % 512 == 0
    f32x4 w;
    w.x = wsrc[0]; w.y = wsrc[1]; w.z = wsrc[2]; w.w = wsrc[3];
    f32x4* j4 = (f32x4*)out_jac;              // 16777216 vec4 slots
    for (int i = i0; i < 16777216; i += nth) {
        __builtin_nontemporal_store(w, j4 + i);
    }
}

// ======================================================================
extern "C" void kernel_launch(void* const* d_in, const int* in_sizes, int n_in,
                              void* d_out, int out_size, void* d_ws, size_t ws_size,
                              hipStream_t stream)
{
    const float* x  = (const float*)d_in[0];
    const float* We = (const float*)d_in[1];
    const float* be = (const float*)d_in[2];
    const float* Wd = (const float*)d_in[3];
    const float* bd = (const float*)d_in[4];
    const float* Ws = (const float*)d_in[5];
    const float* bs = (const float*)d_in[6];

    float* out  = (float*)d_out;
    float* o_y  = out;                 // [16,2048,16]
    float* o_xh = out + 524288;        // [16,2048,128]
    float* o_z  = out + 4718592;       // [16,2048,16]
    float* o_j  = out + 5242880;       // [16,2048,16,128]  (268 MB)
    float* o_Ws = out + 72351744;      // [16,1016]
    float* o_Wd = out + 72368000;      // [128,16]

    float*  z_ws  = o_j + OFF_ZWS;
    float*  a_t   = o_j + OFF_AT;
    float*  p_t   = o_j + OFF_PT;
    float*  wt    = o_j + OFF_WT;
    float*  z_t   = o_j + OFF_ZT;
    double* twc_g = (double*)(o_j + OFF_TWC);
    double* tws_g = (double*)(o_j + OFF_TWS);
    float*  part  = o_j + OFF_PART;    // ends at 6.3M floats << 67.1M region

    hipLaunchKernelGGL(k1_encdec, dim3(2116), dim3(256), 0, stream,
                       x, We, be, Wd, bd, Ws, o_z, o_xh, o_Ws, o_Wd,
                       z_ws, z_t, wt, twc_g, tws_g);
    hipLaunchKernelGGL(k2_hilbert, dim3(256), dim3(1024), 0, stream,
                       z_t, twc_g, tws_g, a_t, p_t);
    hipLaunchKernelGGL(k3_yhat, dim3(256), dim3(256), 0, stream,
                       z_ws, a_t, p_t, wt, part);
    hipLaunchKernelGGL(k3_reduce, dim3(512), dim3(256), 0, stream,
                       part, bs, o_y);
    hipLaunchKernelGGL(k3_jac, dim3(8192), dim3(256), 0, stream,
                       We, o_j);
}

// Round 8
// 388.560 us; speedup vs baseline: 1.5133x; 1.0655x over previous
//
#include <hip/hip_runtime.h>
#include <math.h>

typedef unsigned short u16;
typedef unsigned int   u32;
typedef __attribute__((ext_vector_type(4))) float f32x4;   // native vec for nontemporal

// ---------------- scratch layout (fp32 offsets relative to o_j) ----------------
// Scratch lives at the HEAD of the jac output region. Writer blocks fused into
// k1/k2/k3_yhat stream the jac TAIL (beyond the head) concurrently with compute;
// k4 rewrites the head after k3_reduce has consumed the scratch.
#define OFF_ZWS   0          // z, [bt][16]        524288 f
#define OFF_AT    524288     // |analytic|, [16][32768] (transposed)
#define OFF_PT    1048576    // angle,      [16][32768]
#define OFF_WT    1572864    // W_sindy^T,  [1016][16]  16256 f
#define OFF_ZT    1589120    // z transposed [16][32768]
#define OFF_TWC   2113408    // 1024 doubles (cos)
#define OFF_TWS   2115456    // 1024 doubles (sin)
#define OFF_PART  2117504    // partial y: [8][32768][16] = 4194304 f
// head = 6311808 floats = 1577952 float4 (25 MB)

#define HEAD_F4   1577952
#define R1_LO     1577952    // k1 writers:   [R1_LO, R1_HI)
#define R1_HI     6577952
#define R2_LO     6577952    // k2 writers:   [R2_LO, R2_HI)
#define R2_HI     11577952
#define R3_LO     11577952   // yhat writers: [R3_LO, 16777216)
#define R3_HI     16777216

// jac[b,t,l,f] = W_enc[l,f]: flat f4 index i sources Wenc f4 (i & 511).
// Requires nth % 512 == 0 so the source index is loop-invariant.
__device__ __forceinline__ void jac_range(const float* __restrict__ Wenc,
                                          float* __restrict__ out_jac,
                                          int lo, int hi, int idx, int nth)
{
    const float* wsrc = Wenc + (size_t)((lo + idx) & 511) * 4;
    f32x4 w;
    w.x = wsrc[0]; w.y = wsrc[1]; w.z = wsrc[2]; w.w = wsrc[3];
    f32x4* j4 = (f32x4*)out_jac;
    for (int i = lo + idx; i < hi; i += nth)
        __builtin_nontemporal_store(w, j4 + i);
}

// ======================================================================
// K1: encoder + decoder; tail-util blocks (2048..2115): passthroughs,
//     W_sindy^T, twiddles; writer blocks (>=2116): jac range R1.
// ======================================================================
__global__ __launch_bounds__(256) void k1_encdec(
    const float* __restrict__ x, const float* __restrict__ Wenc, const float* __restrict__ benc,
    const float* __restrict__ Wdec, const float* __restrict__ bdec,
    const float* __restrict__ Wsin,
    float* __restrict__ out_z, float* __restrict__ out_xhat,
    float* __restrict__ out_Ws, float* __restrict__ out_Wd,
    float* __restrict__ z_ws, float* __restrict__ z_t, float* __restrict__ wt,
    double* __restrict__ twc_g, double* __restrict__ tws_g,
    float* __restrict__ out_jac)
{
    int tid = threadIdx.x;
    int blk = blockIdx.x;

    if (blk >= 2116) {       // 1024 writer blocks, nth = 262144 (512 | nth)
        jac_range(Wenc, out_jac, R1_LO, R1_HI, (blk - 2116) * 256 + tid, 262144);
        return;
    }
    if (blk >= 2048) {
        int t0 = (blk - 2048) * 256 + tid;   // 68 blocks -> 17408 threads
        if (t0 < 16256) {
            float v = Wsin[t0];
            out_Ws[t0] = v;
            int l = t0 / 1016;
            int d = t0 - l * 1016;
            wt[d * 16 + l] = v;
        } else if (t0 < 17280) {             // 1024 twiddles, fp64, once
            int k = t0 - 16256;
            double ang = -6.283185307179586476925286766559 * (double)k / 2048.0;
            double s_, c_;
            sincos(ang, &s_, &c_);
            twc_g[k] = c_;
            tws_g[k] = s_;
        }
        if (t0 < 2048) out_Wd[t0] = Wdec[t0];
        return;
    }

    __shared__ float xs[16][128];
    __shared__ float we[16][132];
    __shared__ float wd[128][17];
    __shared__ float zs[16][16];

    {
        const float4* xv = (const float4*)x + (size_t)blk * 512;
        float* dst = &xs[0][0];
        float4 a = xv[tid], b = xv[tid + 256];
        dst[tid*4+0]=a.x; dst[tid*4+1]=a.y; dst[tid*4+2]=a.z; dst[tid*4+3]=a.w;
        dst[(tid+256)*4+0]=b.x; dst[(tid+256)*4+1]=b.y; dst[(tid+256)*4+2]=b.z; dst[(tid+256)*4+3]=b.w;
    }
    {
        const float4* wev = (const float4*)Wenc;
        #pragma unroll
        for (int h = 0; h < 2; ++h) {
            int vi = tid + h * 256;
            float4 v = wev[vi];
            int base = vi * 4, row = base >> 7, col = base & 127;
            we[row][col+0]=v.x; we[row][col+1]=v.y; we[row][col+2]=v.z; we[row][col+3]=v.w;
        }
    }
    {
        const float4* wdv = (const float4*)Wdec;
        #pragma unroll
        for (int h = 0; h < 2; ++h) {
            int vi = tid + h * 256;
            float4 v = wdv[vi];
            int base = vi * 4, row = base >> 4, col = base & 15;
            wd[row][col+0]=v.x; wd[row][col+1]=v.y; wd[row][col+2]=v.z; wd[row][col+3]=v.w;
        }
    }
    __syncthreads();

    {
        int r = tid >> 4, l = tid & 15;
        float s = 0.f;
        #pragma unroll 8
        for (int f = 0; f < 128; ++f) s += xs[r][f] * we[l][f];
        float zv = s + benc[l];
        zs[r][l] = zv;
        int zo = blk * 256 + tid;             // == (blk*16+r)*16 + l
        z_ws[zo]  = zv;
        out_z[zo] = zv;
    }
    __syncthreads();

    {   // transposed z copy for K2 (coalesced 64B runs)
        int l2 = tid >> 4, r2 = tid & 15;
        z_t[l2 * 32768 + blk * 16 + r2] = zs[r2][l2];
    }

    #pragma unroll
    for (int u = 0; u < 8; ++u) {
        int idx = u * 256 + tid;
        int rr = idx >> 7, f = idx & 127;
        float acc = bdec[f];
        #pragma unroll
        for (int ll = 0; ll < 16; ++ll) acc += zs[rr][ll] * wd[f][ll];
        out_xhat[(size_t)blk * 2048 + idx] = acc;
    }
}

// ======================================================================
// K2: Hilbert per (b,l), fp64 interleaved-complex LDS FFT (DIF fwd ->
//     filter in bitrev domain -> DIT inv, no permutes). Blocks >=256:
//     jac range R2 (1 co-resident writer/CU keeps HBM busy during FFT).
// ======================================================================
__global__ __launch_bounds__(1024) void k2_hilbert(
    const float* __restrict__ z_t, const double* __restrict__ twc_g,
    const double* __restrict__ tws_g, const float* __restrict__ Wenc,
    float* __restrict__ a_t, float* __restrict__ p_t,
    float* __restrict__ out_jac)
{
    __shared__ double2 c[2048];    // interleaved complex, ds_*_b128
    __shared__ double2 tw[1024];   // (cos,sin) of -2*pi*k/2048

    int tid = threadIdx.x;
    if (blockIdx.x >= 256) {       // 512 writer blocks, nth = 524288
        jac_range(Wenc, out_jac, R2_LO, R2_HI, (blockIdx.x - 256) * 1024 + tid, 524288);
        return;
    }
    int b = blockIdx.x >> 4, l = blockIdx.x & 15;
    const size_t base = (size_t)l * 32768 + (size_t)b * 2048;
    const float* zp = z_t + base;

    {
        double2 t; t.x = twc_g[tid]; t.y = tws_g[tid];
        tw[tid] = t;
    }
    {
        double2 v0; v0.x = (double)zp[tid];        v0.y = 0.0;
        double2 v1; v1.x = (double)zp[tid + 1024]; v1.y = 0.0;
        c[tid] = v0;
        c[tid + 1024] = v1;
    }
    __syncthreads();

    // forward DIF: u'=u+v, v'=(u-v)*W^(j*step)
    for (int half = 1024; half >= 1; half >>= 1) {
        int step = 1024 / half;
        int j = tid & (half - 1);
        int pos = ((tid - j) << 1) + j;
        double2 u = c[pos], v = c[pos + half];
        double2 w = tw[j * step];
        double2 s, dsc;
        s.x = u.x + v.x;  s.y = u.y + v.y;
        double br = u.x - v.x, bi = u.y - v.y;
        dsc.x = br * w.x - bi * w.y;
        dsc.y = br * w.y + bi * w.x;
        c[pos] = s;
        c[pos + half] = dsc;
        __syncthreads();
    }

    // Hilbert filter in bitrev domain (k==0 <-> p==0, k>=1024 <-> p odd), 1/N folded
    #pragma unroll
    for (int h = 0; h < 2; ++h) {
        int t = tid + h * 1024;
        double sc = (t == 0 || (t & 1)) ? 0.0 : (2.0 / 2048.0);
        double2 v = c[t];
        v.x *= sc; v.y *= sc;
        c[t] = v;
    }
    __syncthreads();

    // inverse DIT: t = v*conj(W); u'=u+t, v'=u-t
    for (int half = 1; half <= 1024; half <<= 1) {
        int step = 1024 / half;
        int j = tid & (half - 1);
        int pos = ((tid - j) << 1) + j;
        double2 u = c[pos], v = c[pos + half];
        double2 w = tw[j * step];
        double tr = v.x * w.x + v.y * w.y;
        double ti = v.y * w.x - v.x * w.y;
        double2 p0, p1;
        p0.x = u.x + tr; p0.y = u.y + ti;
        p1.x = u.x - tr; p1.y = u.y - ti;
        c[pos] = p0;
        c[pos + half] = p1;
        __syncthreads();
    }

    #pragma unroll
    for (int h = 0; h < 2; ++h) {
        int t = tid + h * 1024;
        double2 v = c[t];
        a_t[base + t] = (float)sqrt(v.x * v.x + v.y * v.y);
        p_t[base + t] = (float)atan2(v.y, v.x);
    }
}

// ======================================================================
// K3a: y partials. 512 compute blocks = 8 slices x 64 pt-groups, 2 pts/thread
//      (~170 VGPR, no spills, 2 blocks/CU). Blocks >=512: jac range R3.
// ======================================================================
#define EMIT2(EXPR) do {                                                    \
    if ((unsigned)(d - LO) < 127u) {                                        \
        float vv[2];                                                        \
        _Pragma("unroll") for (int p = 0; p < 2; ++p) vv[p] = (EXPR);       \
        int bb = (d - LO) << 4;                                             \
        _Pragma("unroll") for (int l = 0; l < 16; ++l) {                    \
            float w = lw[bb + l];                                           \
            acc[0][l] = fmaf(vv[0], w, acc[0][l]);                          \
            acc[1][l] = fmaf(vv[1], w, acc[1][l]);                          \
        }                                                                   \
    }                                                                       \
    ++d;                                                                    \
} while (0)

__global__ __launch_bounds__(256, 2) void k3_yhat(
    const float* __restrict__ z_ws, const float* __restrict__ a_t,
    const float* __restrict__ p_t, const float* __restrict__ wt,
    const float* __restrict__ Wenc,
    float* __restrict__ part, float* __restrict__ out_jac)
{
    __shared__ float lw[2032];                // 127 features x 16
    int tid = threadIdx.x;
    if (blockIdx.x >= 512) {                  // 1024 writer blocks, nth = 262144
        jac_range(Wenc, out_jac, R3_LO, R3_HI, (blockIdx.x - 512) * 256 + tid, 262144);
        return;
    }
    int slice = blockIdx.x >> 6;              // 0..7
    int ptgrp = blockIdx.x & 63;              // 0..63
    int LO = slice * 127;
    int base = ptgrp * 512;                   // 512 points per block

    {   // stage slice weights: 508 float4
        const float4* src = (const float4*)(wt + LO * 16);
        float4* dst = (float4*)lw;
        for (int i = tid; i < 508; i += 256) dst[i] = src[i];
    }
    __syncthreads();

    float z[2][16], av[2][16], pv[2][16], acc[2][16];
    #pragma unroll
    for (int p = 0; p < 2; ++p) {
        int bt = base + p * 256 + tid;
        const float4* zp = (const float4*)(z_ws + (size_t)bt * 16);
        #pragma unroll
        for (int q = 0; q < 4; ++q) {
            float4 v = zp[q];
            z[p][q*4+0]=v.x; z[p][q*4+1]=v.y; z[p][q*4+2]=v.z; z[p][q*4+3]=v.w;
        }
    }
    if (LO >= 880) {                          // only slice 7 touches av/pv
        #pragma unroll
        for (int p = 0; p < 2; ++p) {
            int bt = base + p * 256 + tid;
            #pragma unroll
            for (int l = 0; l < 16; ++l) {
                av[p][l] = a_t[(size_t)l * 32768 + bt];
                pv[p][l] = p_t[(size_t)l * 32768 + bt];
            }
        }
    } else {
        #pragma unroll
        for (int p = 0; p < 2; ++p)
            #pragma unroll
            for (int l = 0; l < 16; ++l) { av[p][l] = 0.f; pv[p][l] = 0.f; }
    }
    #pragma unroll
    for (int p = 0; p < 2; ++p)
        #pragma unroll
        for (int l = 0; l < 16; ++l) acc[p][l] = 0.f;   // bias added in reduce

    int d = 0;
    #pragma unroll
    for (int i = 0; i < 16; ++i) EMIT2(z[p][i]);                          // deg 1
    #pragma unroll
    for (int i = 0; i < 16; ++i)
        #pragma unroll
        for (int j = i; j < 16; ++j) EMIT2(z[p][i] * z[p][j]);            // deg 2
    #pragma unroll
    for (int i = 0; i < 16; ++i)
        #pragma unroll
        for (int j = i; j < 16; ++j)
            #pragma unroll
            for (int k = j; k < 16; ++k) EMIT2(z[p][i] * z[p][j] * z[p][k]); // deg 3
    #pragma unroll
    for (int i = 0; i < 16; ++i) EMIT2(z[p][i]);                          // z
    #pragma unroll
    for (int i = 0; i < 16; ++i) EMIT2(av[p][i]);                         // |analytic|
    #pragma unroll
    for (int i = 0; i < 16; ++i) EMIT2(pv[p][i]);                         // angle

    #pragma unroll
    for (int p = 0; p < 2; ++p) {
        int bt = base + p * 256 + tid;
        float4* pp = (float4*)(part + (size_t)slice * 524288 + (size_t)bt * 16);
        #pragma unroll
        for (int q = 0; q < 4; ++q) {
            float4 v;
            v.x = acc[p][q*4+0]; v.y = acc[p][q*4+1];
            v.z = acc[p][q*4+2]; v.w = acc[p][q*4+3];
            pp[q] = v;
        }
    }
}

// ======================================================================
// K3b: reduce 8 partials + bias -> y_hat. 131072 float4 outputs.
// ======================================================================
__global__ __launch_bounds__(256) void k3_reduce(
    const float* __restrict__ part, const float* __restrict__ bsin,
    float* __restrict__ out_y)
{
    int i0 = blockIdx.x * 256 + threadIdx.x;      // float4 index
    float4 s = ((const float4*)bsin)[i0 & 3];
    const float4* p4 = (const float4*)part;
    #pragma unroll
    for (int sl = 0; sl < 8; ++sl) {
        float4 v = p4[(size_t)sl * 131072 + i0];
        s.x += v.x; s.y += v.y; s.z += v.z; s.w += v.w;
    }
    ((float4*)out_y)[i0] = s;
}

// ======================================================================
// K4: rewrite the scratch HEAD of the jac region (25 MB). Runs LAST.
// ======================================================================
__global__ __launch_bounds__(256) void k4_jac_head(
    const float* __restrict__ Wenc, float* __restrict__ out_jac)
{
    // 1536 blocks: nth = 393216 (divisible by 512)
    jac_range(Wenc, out_jac, 0, HEAD_F4, blockIdx.x * 256 + threadIdx.x, 393216);
}

// ======================================================================
extern "C" void kernel_launch(void* const* d_in, const int* in_sizes, int n_in,
                              void* d_out, int out_size, void* d_ws, size_t ws_size,
                              hipStream_t stream)
{
    const float* x  = (const float*)d_in[0];
    const float* We = (const float*)d_in[1];
    const float* be = (const float*)d_in[2];
    const float* Wd = (const float*)d_in[3];
    const float* bd = (const float*)d_in[4];
    const float* Ws = (const float*)d_in[5];
    const float* bs = (const float*)d_in[6];

    float* out  = (float*)d_out;
    float* o_y  = out;                 // [16,2048,16]
    float* o_xh = out + 524288;        // [16,2048,128]
    float* o_z  = out + 4718592;       // [16,2048,16]
    float* o_j  = out + 5242880;       // [16,2048,16,128]  (268 MB)
    float* o_Ws = out + 72351744;      // [16,1016]
    float* o_Wd = out + 72368000;      // [128,16]

    float*  z_ws  = o_j + OFF_ZWS;
    float*  a_t   = o_j + OFF_AT;
    float*  p_t   = o_j + OFF_PT;
    float*  wt    = o_j + OFF_WT;
    float*  z_t   = o_j + OFF_ZT;
    double* twc_g = (double*)(o_j + OFF_TWC);
    double* tws_g = (double*)(o_j + OFF_TWS);
    float*  part  = o_j + OFF_PART;

    hipLaunchKernelGGL(k1_encdec, dim3(3140), dim3(256), 0, stream,
                       x, We, be, Wd, bd, Ws, o_z, o_xh, o_Ws, o_Wd,
                       z_ws, z_t, wt, twc_g, tws_g, o_j);
    hipLaunchKernelGGL(k2_hilbert, dim3(768), dim3(1024), 0, stream,
                       z_t, twc_g, tws_g, We, a_t, p_t, o_j);
    hipLaunchKernelGGL(k3_yhat, dim3(1536), dim3(256), 0, stream,
                       z_ws, a_t, p_t, wt, We, part, o_j);
    hipLaunchKernelGGL(k3_reduce, dim3(512), dim3(256), 0, stream,
                       part, bs, o_y);
    hipLaunchKernelGGL(k4_jac_head, dim3(1536), dim3(256), 0, stream,
                       We, o_j);
}